// Round 2
// baseline (3597.367 us; speedup 1.0000x reference)
//
#include <hip/hip_runtime.h>
#include <cstdint>
#include <cstddef>

#define B_SZ   4096
#define NF     26
#define VOC    100000
#define DD     64
#define LDH    3088   // padded row stride of hmat (3072 flat + 13 dense + 3 pad)
#define DIN    3085

__device__ __forceinline__ float fast_tanh(float x) {
    // exact identity tanh(x) = 1 - 2/(e^{2x}+1); __expf -> v_exp_f32, rcp -> v_rcp_f32
    float e = __expf(2.0f * x);
    return 1.0f - 2.0f * __builtin_amdgcn_rcpf(e + 1.0f);
}

template<int N>
__device__ __forceinline__ void bitonic_asc(float (&a)[N]) {
#pragma unroll
    for (int k = 2; k <= N; k <<= 1) {
#pragma unroll
        for (int j = k >> 1; j > 0; j >>= 1) {
#pragma unroll
            for (int i = 0; i < N; ++i) {
                int l = i ^ j;
                if (l > i) {
                    bool up = ((i & k) == 0);
                    float x = a[i], y = a[l];
                    float mn = fminf(x, y), mx = fmaxf(x, y);
                    a[i] = up ? mn : mx;
                    a[l] = up ? mx : mn;
                }
            }
        }
    }
}

// ---------------------------------------------------------------------------
// prep: transpose conv weights to lane-contiguous layouts, zero BN accums,
// copy dense cols into hmat[:, 3072:3085]
// ---------------------------------------------------------------------------
__global__ void prep_kernel(const float* __restrict__ cw1, const float* __restrict__ cw2,
                            const float* __restrict__ cw3, const float* __restrict__ dense,
                            float* __restrict__ w1t, float* __restrict__ w2t,
                            float* __restrict__ w3t, float* __restrict__ sums,
                            float* __restrict__ hmat)
{
    int idx = blockIdx.x * blockDim.x + threadIdx.x;
    if (idx < 448) {                       // cw1 (64,7) -> w1t[j*64+c]
        int c = idx / 7, j = idx % 7;
        w1t[j * 64 + c] = cw1[idx];
    } else if (idx < 10688) {              // cw2 (32,64,5) -> w2t[(c*5+j)*32+c2]
        int t = idx - 448;
        int c2 = t / 320, r = t % 320;     // r = c*5+j
        w2t[r * 32 + c2] = cw2[t];
    } else if (idx < 12224) {              // cw3 (16,32,3) -> w3t[(cc*3+j)*16+c3]
        int t = idx - 10688;
        int c3 = t / 96, r = t % 96;       // r = cc*3+j
        w3t[r * 16 + c3] = cw3[t];
    } else if (idx < 12992) {              // zero sums1/sumsq1/sums2/sumsq2 (768)
        sums[idx - 12224] = 0.f;
    }
    int di = idx - 12992;
    if (di >= 0 && di < B_SZ * 13) {
        int b = di / 13, j = di % 13;
        hmat[(size_t)b * LDH + 3072 + j] = dense[di];
    }
}

// ---------------------------------------------------------------------------
// fused embedding gather + conv1/topk23 + conv2/topk8 + conv3/topk3
// one wave (64 threads) per (b, d) pair; grid (64, 4096)
// ---------------------------------------------------------------------------
__global__ __launch_bounds__(64) void cnn_kernel(
    const int* __restrict__ sparse, const float* __restrict__ tables,
    const float* __restrict__ w1t, const float* __restrict__ cb1,
    const float* __restrict__ w2t, const float* __restrict__ cb2,
    const float* __restrict__ w3t, const float* __restrict__ cb3,
    float* __restrict__ hmat)
{
    const int d = blockIdx.x;
    const int b = blockIdx.y;
    const int tid = threadIdx.x;

    __shared__ float h0s[32];
    __shared__ __align__(16) float t1c[64 * 28];  // [c][i], i = f+2, zeros at 0,1,25,26,27
    __shared__ float y2l[32 * 25];                // [c2][f] stride 25 (coprime w/ 32)
    __shared__ float t2s[32 * 10];                // [c2][i], i = f+1, zeros at 0,9
    __shared__ float y3l[16 * 9];                 // [c3][f]

    if (tid < 32) h0s[tid] = 0.0f;
    __syncthreads();
    if (tid < NF) {
        int idx = sparse[b * NF + tid];
        h0s[3 + tid] = tables[((size_t)tid * VOC + idx) * DD + d];
    }
    __syncthreads();

    // ---- conv1 + tanh + top-23 (thread = channel c) ----
    {
        const int c = tid;
        float w1r[7];
#pragma unroll
        for (int j = 0; j < 7; ++j) w1r[j] = w1t[j * 64 + c];
        float bias = cb1[c];
        float hr[32];
#pragma unroll
        for (int i = 0; i < 32; ++i) hr[i] = h0s[i];
        float arr[32];
#pragma unroll
        for (int f = 0; f < 26; ++f) {
            float s = bias;
#pragma unroll
            for (int j = 0; j < 7; ++j) s += w1r[j] * hr[f + j];
            arr[f] = fast_tanh(s);
        }
#pragma unroll
        for (int f = 26; f < 32; ++f) arr[f] = -2.0f;   // pad below tanh range
        bitonic_asc<32>(arr);
        float* row = &t1c[c * 28];
        row[0] = 0.f; row[1] = 0.f; row[25] = 0.f; row[26] = 0.f; row[27] = 0.f;
#pragma unroll
        for (int f = 0; f < 23; ++f) row[2 + f] = arr[31 - f];  // descending
    }
    __syncthreads();

    // ---- conv2 + tanh : thread (c2 = tid&31, f-half = tid>>5) ----
    {
        const int c2 = tid & 31;
        const int h = tid >> 5;
        const int f0 = h * 12;
        const int nf = h ? 11 : 12;
        float acc[12];
        float bias = cb2[c2];
#pragma unroll
        for (int q = 0; q < 12; ++q) acc[q] = bias;
        for (int c = 0; c < 64; ++c) {
            const float4* trow = reinterpret_cast<const float4*>(&t1c[c * 28 + f0]);
            float4 v0 = trow[0], v1 = trow[1], v2 = trow[2], v3 = trow[3];
            float x[16] = {v0.x,v0.y,v0.z,v0.w, v1.x,v1.y,v1.z,v1.w,
                           v2.x,v2.y,v2.z,v2.w, v3.x,v3.y,v3.z,v3.w};
            float w[5];
#pragma unroll
            for (int j = 0; j < 5; ++j) w[j] = w2t[(c * 5 + j) * 32 + c2];
#pragma unroll
            for (int q = 0; q < 12; ++q) {
#pragma unroll
                for (int j = 0; j < 5; ++j) acc[q] += w[j] * x[q + j];
            }
        }
#pragma unroll
        for (int q = 0; q < 12; ++q)
            if (q < nf) y2l[c2 * 25 + f0 + q] = fast_tanh(acc[q]);
    }
    __syncthreads();

    // ---- top-8 of 23 per c2 ----
    if (tid < 32) {
        float a[32];
#pragma unroll
        for (int f = 0; f < 23; ++f) a[f] = y2l[tid * 25 + f];
#pragma unroll
        for (int f = 23; f < 32; ++f) a[f] = -2.0f;
        bitonic_asc<32>(a);
        float* row = &t2s[tid * 10];
        row[0] = 0.f; row[9] = 0.f;
#pragma unroll
        for (int i = 0; i < 8; ++i) row[1 + i] = a[31 - i];
    }
    __syncthreads();

    // ---- conv3 + tanh : 2 outputs per thread ----
    {
#pragma unroll
        for (int o = 0; o < 2; ++o) {
            int idx = tid + o * 64;
            int c3 = idx & 15;
            int f = idx >> 4;
            float s = cb3[c3];
            for (int cc = 0; cc < 32; ++cc) {
#pragma unroll
                for (int j = 0; j < 3; ++j)
                    s += w3t[(cc * 3 + j) * 16 + c3] * t2s[cc * 10 + f + j];
            }
            y3l[c3 * 9 + f] = fast_tanh(s);
        }
    }
    __syncthreads();

    // ---- top-3 of 8 per c3, write flat ----
    if (tid < 16) {
        float a[8];
#pragma unroll
        for (int f = 0; f < 8; ++f) a[f] = y3l[tid * 9 + f];
        bitonic_asc<8>(a);
        float* orow = &hmat[(size_t)b * LDH + tid * 192 + d];
        orow[0]   = a[7];
        orow[64]  = a[6];
        orow[128] = a[5];
    }
}

// ---------------------------------------------------------------------------
// fp32 tiled GEMM: C[M,N] = A(act) @ B;  64x64 tile, 4x4 per thread, BK=16.
// APPLY: A elements transformed tanh(v*scl[k]+sft[k]) on load (BN+tanh fold).
// ---------------------------------------------------------------------------
template<bool APPLY>
__global__ __launch_bounds__(256) void gemm_kernel(
    const float* __restrict__ A, int lda, int K,
    const float* __restrict__ Bm, int ldb,
    const float* __restrict__ scl, const float* __restrict__ sft,
    float* __restrict__ C, int N)
{
    __shared__ __align__(16) float As[16 * 68];
    __shared__ __align__(16) float Bs[16 * 68];
    const int tid = threadIdx.x;
    const int row0 = blockIdx.y * 64;
    const int n0 = blockIdx.x * 64;
    const int ty = tid >> 4, tx = tid & 15;

    float acc[4][4];
#pragma unroll
    for (int i = 0; i < 4; ++i)
#pragma unroll
        for (int j = 0; j < 4; ++j) acc[i][j] = 0.f;

    const int kk_a = tid & 15, rb_a = tid >> 4;
    const int kr_b = tid >> 4, nb_b = (tid & 15) * 4;

    for (int k0 = 0; k0 < K; k0 += 16) {
        __syncthreads();
        {   // A tile -> As[k][m]
            int k = k0 + kk_a;
            bool ok = (k < K);
            float sc = 0.f, sh = 0.f;
            if (APPLY && ok) { sc = scl[k]; sh = sft[k]; }
#pragma unroll
            for (int p = 0; p < 4; ++p) {
                int r = rb_a + p * 16;
                float v = 0.f;
                if (ok) {
                    v = A[(size_t)(row0 + r) * lda + k];
                    if (APPLY) v = fast_tanh(v * sc + sh);
                }
                As[kk_a * 68 + r] = v;
            }
        }
        {   // B tile -> Bs[k][n]
            int k = k0 + kr_b;
            float4 bv = make_float4(0.f, 0.f, 0.f, 0.f);
            if (k < K) bv = *reinterpret_cast<const float4*>(&Bm[(size_t)k * ldb + n0 + nb_b]);
            *reinterpret_cast<float4*>(&Bs[kr_b * 68 + nb_b]) = bv;
        }
        __syncthreads();
#pragma unroll
        for (int kk = 0; kk < 16; ++kk) {
            float4 av = *reinterpret_cast<const float4*>(&As[kk * 68 + ty * 4]);
            float4 bv = *reinterpret_cast<const float4*>(&Bs[kk * 68 + tx * 4]);
            float aa[4] = {av.x, av.y, av.z, av.w};
            float bb[4] = {bv.x, bv.y, bv.z, bv.w};
#pragma unroll
            for (int i = 0; i < 4; ++i)
#pragma unroll
                for (int j = 0; j < 4; ++j) acc[i][j] += aa[i] * bb[j];
        }
    }

#pragma unroll
    for (int i = 0; i < 4; ++i) {
        float4 ov = make_float4(acc[i][0], acc[i][1], acc[i][2], acc[i][3]);
        *reinterpret_cast<float4*>(&C[(size_t)(row0 + ty * 4 + i) * N + n0 + tx * 4]) = ov;
    }
}

// ---------------------------------------------------------------------------
// BN column stats: block = ncols threads, each block sums 256 rows, atomics out
// ---------------------------------------------------------------------------
__global__ void bnstats_kernel(const float* __restrict__ z, int ncols,
                               float* __restrict__ sums, float* __restrict__ sumsq)
{
    int col = threadIdx.x;
    int r0 = blockIdx.x * 256;
    float s = 0.f, q = 0.f;
    for (int i = 0; i < 256; ++i) {
        float v = z[(size_t)(r0 + i) * ncols + col];
        s += v; q += v * v;
    }
    atomicAdd(&sums[col], s);
    atomicAdd(&sumsq[col], q);
}

__global__ void bnfin_kernel(const float* __restrict__ sums, const float* __restrict__ sumsq,
                             const float* __restrict__ g, const float* __restrict__ be,
                             int ncols, float* __restrict__ scl, float* __restrict__ sft)
{
    int i = threadIdx.x + blockIdx.x * blockDim.x;
    if (i < ncols) {
        float mu = sums[i] * (1.0f / 4096.0f);
        float var = sumsq[i] * (1.0f / 4096.0f) - mu * mu;
        float s = g[i] * rsqrtf(var + 1e-5f);
        scl[i] = s;
        sft[i] = be[i] - mu * s;
    }
}

// out[r] = b3 + sum_n tanh(z2[r,n]*scl[n]+sft[n]) * W3[n]; one wave per row
__global__ __launch_bounds__(256) void final_kernel(
    const float* __restrict__ z2, const float* __restrict__ scl, const float* __restrict__ sft,
    const float* __restrict__ W3, const float* __restrict__ b3, float* __restrict__ out)
{
    int lane = threadIdx.x & 63;
    int wv = threadIdx.x >> 6;
    int r = blockIdx.x * 4 + wv;
    float p = 0.f;
#pragma unroll
    for (int t = 0; t < 2; ++t) {
        int n = lane + t * 64;
        p += fast_tanh(z2[(size_t)r * 128 + n] * scl[n] + sft[n]) * W3[n];
    }
#pragma unroll
    for (int off = 32; off > 0; off >>= 1) p += __shfl_down(p, off);
    if (lane == 0) out[r] = p + b3[0];
}

extern "C" void kernel_launch(void* const* d_in, const int* in_sizes, int n_in,
                              void* d_out, int out_size, void* d_ws, size_t ws_size,
                              hipStream_t stream) {
    const int*   sparse = (const int*)  d_in[0];
    const float* dense  = (const float*)d_in[1];
    const float* tables = (const float*)d_in[2];
    const float* cw1    = (const float*)d_in[3];
    const float* cb1    = (const float*)d_in[4];
    const float* cw2    = (const float*)d_in[5];
    const float* cb2    = (const float*)d_in[6];
    const float* cw3    = (const float*)d_in[7];
    const float* cb3    = (const float*)d_in[8];
    const float* W1     = (const float*)d_in[9];
    // d_in[10] = b1 (zeros; cancels under BN)
    const float* g1     = (const float*)d_in[11];
    const float* be1    = (const float*)d_in[12];
    const float* W2     = (const float*)d_in[13];
    // d_in[14] = b2 (cancels under BN)
    const float* g2     = (const float*)d_in[15];
    const float* be2    = (const float*)d_in[16];
    const float* W3     = (const float*)d_in[17];
    const float* b3     = (const float*)d_in[18];
    float* out = (float*)d_out;

    float* ws   = (float*)d_ws;
    float* hmat = ws;                                  // 4096*3088
    float* z1   = hmat + (size_t)B_SZ * LDH;           // 4096*256
    float* z2   = z1 + (size_t)B_SZ * 256;             // 4096*128
    float* w1t  = z2 + (size_t)B_SZ * 128;             // 448
    float* w2t  = w1t + 448;                           // 10240
    float* w3t  = w2t + 10240;                         // 1536
    float* sums = w3t + 1536;                          // 768 = s1(256) q1(256) s2(128) q2(128)
    float* a1   = sums + 768;                          // 256
    float* c1   = a1 + 256;                            // 256
    float* a2   = c1 + 256;                            // 128
    float* c2v  = a2 + 128;                            // 128

    prep_kernel<<<259, 256, 0, stream>>>(cw1, cw2, cw3, dense, w1t, w2t, w3t, sums, hmat);

    dim3 cg(DD, B_SZ);
    cnn_kernel<<<cg, 64, 0, stream>>>(sparse, tables, w1t, cb1, w2t, cb2, w3t, cb3, hmat);

    gemm_kernel<false><<<dim3(4, 64), 256, 0, stream>>>(hmat, LDH, DIN, W1, 256,
                                                        nullptr, nullptr, z1, 256);
    bnstats_kernel<<<16, 256, 0, stream>>>(z1, 256, sums, sums + 256);
    bnfin_kernel<<<1, 256, 0, stream>>>(sums, sums + 256, g1, be1, 256, a1, c1);

    gemm_kernel<true><<<dim3(2, 64), 256, 0, stream>>>(z1, 256, 256, W2, 128,
                                                       a1, c1, z2, 128);
    bnstats_kernel<<<16, 128, 0, stream>>>(z2, 128, sums + 512, sums + 640);
    bnfin_kernel<<<1, 128, 0, stream>>>(sums + 512, sums + 640, g2, be2, 128, a2, c2v);

    final_kernel<<<1024, 256, 0, stream>>>(z2, a2, c2v, W3, b3, out);
}

// Round 3
// 1800.074 us; speedup vs baseline: 1.9985x; 1.9985x over previous
//
#include <hip/hip_runtime.h>
#include <cstdint>
#include <cstddef>

#define B_SZ   4096
#define NF     26
#define VOC    100000
#define LDH    3088   // padded row stride of hmat (3072 flat + 13 dense + 3 pad)
#define DIN    3085

typedef __attribute__((ext_vector_type(8))) short short8;   // 8 bf16 (4 VGPRs)
typedef __attribute__((ext_vector_type(4))) float f32x4;

__device__ __forceinline__ float fast_tanh(float x) {
    float e = __expf(2.0f * x);
    return 1.0f - 2.0f * __builtin_amdgcn_rcpf(e + 1.0f);
}
__device__ __forceinline__ unsigned short f2bf(float x) {   // RNE float->bf16
    union { float f; unsigned u; } v; v.f = x;
    return (unsigned short)((v.u + 0x7FFFu + ((v.u >> 16) & 1u)) >> 16);
}
__device__ __forceinline__ float bf2f(unsigned short u) {
    union { unsigned u; float f; } v; v.u = ((unsigned)u) << 16; return v.f;
}

template<int N>
__device__ __forceinline__ void bitonic_asc(float (&a)[N]) {
#pragma unroll
    for (int k = 2; k <= N; k <<= 1) {
#pragma unroll
        for (int j = k >> 1; j > 0; j >>= 1) {
#pragma unroll
            for (int i = 0; i < N; ++i) {
                int l = i ^ j;
                if (l > i) {
                    bool up = ((i & k) == 0);
                    float x = a[i], y = a[l];
                    float mn = fminf(x, y), mx = fmaxf(x, y);
                    a[i] = up ? mn : mx;
                    a[l] = up ? mx : mn;
                }
            }
        }
    }
}

// ---------------------------------------------------------------------------
// prep: conv weights -> MFMA-friendly layouts, zero BN accums, dense -> hmat
//   w1t [j][64c] fp32 (448)
//   w2b [c2][k=j*64+c] bf16 (32*320)
//   w3b [c3][k=j*32+cc] bf16 (16*96)
// ---------------------------------------------------------------------------
__global__ void prep_kernel(const float* __restrict__ cw1, const float* __restrict__ cw2,
                            const float* __restrict__ cw3, const float* __restrict__ dense,
                            float* __restrict__ w1t, unsigned short* __restrict__ w2b,
                            unsigned short* __restrict__ w3b, float* __restrict__ sums,
                            float* __restrict__ hmat)
{
    int idx = blockIdx.x * blockDim.x + threadIdx.x;
    if (idx < 448) {                       // cw1 (64,7) -> w1t[j*64+c]
        int c = idx / 7, j = idx % 7;
        w1t[j * 64 + c] = cw1[idx];
    } else if (idx < 10688) {              // cw2 (32,64,5) -> w2b[c2*320 + j*64+c]
        int o = idx - 448;
        int c2 = o / 320, k = o % 320;
        int j = k >> 6, c = k & 63;
        w2b[o] = f2bf(cw2[(c2 * 64 + c) * 5 + j]);
    } else if (idx < 12224) {              // cw3 (16,32,3) -> w3b[c3*96 + j*32+cc]
        int o = idx - 10688;
        int c3 = o / 96, k = o % 96;
        int j = k >> 5, cc = k & 31;
        w3b[o] = f2bf(cw3[(c3 * 32 + cc) * 3 + j]);
    } else if (idx < 12992) {              // zero BN accums (768)
        sums[idx - 12224] = 0.f;
    }
    int di = idx - 12992;
    if (di >= 0 && di < B_SZ * 13) {
        int b = di / 13, j = di % 13;
        hmat[(size_t)b * LDH + 3072 + j] = dense[di];
    }
}

// ---------------------------------------------------------------------------
// fused CNN: block = 256 thr (4 waves), 8 (b,d) pairs (same b, d0=blockIdx.x*8)
// Phase A: conv1 fp32 + tanh + top23 -> t1s bf16 [dd][i=0..27][c] (stride 1800)
// Phase B: conv2 via MFMA 16x16x32 (M=(e,dd), N=c2, K=320) -> tanh -> y2s bf16
// Phase C: top-8 of 23 -> t2bf [dd][i=0..9][cc] (stride 328)
// Phase D: conv3 via MFMA (K=96) -> tanh -> y3s
// Phase E: top-3 of 8 -> hmat
// ---------------------------------------------------------------------------
__global__ __launch_bounds__(256, 3) void cnn_kernel(
    const int* __restrict__ sparse, const float* __restrict__ tables,
    const float* __restrict__ w1t, const float* __restrict__ cb1,
    const unsigned short* __restrict__ w2b, const float* __restrict__ cb2,
    const unsigned short* __restrict__ w3b, const float* __restrict__ cb3,
    float* __restrict__ hmat)
{
    const int d0 = blockIdx.x * 8;
    const int b  = blockIdx.y;
    const int tid = threadIdx.x;

    __shared__ __align__(16) unsigned short t1s[8 * 1800]; // [dd][28][64c]+pad8
    __shared__ __align__(16) unsigned short y2s[8 * 32 * 25];
    __shared__ __align__(16) unsigned short t2bf[8 * 328]; // [dd][10][32cc]+pad8
    __shared__ __align__(16) float h0s[8 * 32];
    __shared__ __align__(16) float y3s[8 * 128];           // [dd][c3][8f]
    __shared__ int sidx[NF];

    if (tid < NF) sidx[tid] = sparse[b * NF + tid];
    __syncthreads();

    // ---- phase 0: zero pads + embedding gather ----
    for (int x = tid; x < 2560; x += 256) {      // t1s pads i in {0,1,25,26,27}
        int dd = x / 320, r = x % 320;
        int i5 = r >> 6, c = r & 63;
        int i = (i5 < 2) ? i5 : (23 + i5);
        t1s[dd * 1800 + i * 64 + c] = 0;
    }
    for (int x = tid; x < 512; x += 256) {       // t2bf pads i in {0,9}
        int dd = x >> 6, r = x & 63;
        int i = (r >> 5) * 9, cc = r & 31;
        t2bf[dd * 328 + i * 32 + cc] = 0;
    }
    if (tid < 48) {                              // h0s pads i in {0,1,2,29,30,31}
        int dd = tid / 6, r = tid % 6;
        int i = (r < 3) ? r : (26 + r);
        h0s[dd * 32 + i] = 0.f;
    } else {                                     // gather 26 feat x 8 dd
        int t = tid - 48;                        // t < 208
        if (t < 208) {
            int fi = t >> 3, dd = t & 7;
            h0s[dd * 32 + 3 + fi] =
                tables[((size_t)fi * VOC + sidx[fi]) * 64 + d0 + dd];
        }
    }
    __syncthreads();

    // ---- phase A: conv1 + tanh + top-23 (512 tasks, 2/thread) ----
#pragma unroll
    for (int t = 0; t < 2; ++t) {
        int task = tid + 256 * t;
        int dd = task >> 6, c = task & 63;
        float w1r[7];
#pragma unroll
        for (int j = 0; j < 7; ++j) w1r[j] = w1t[j * 64 + c];
        float bias = cb1[c];
        float hr[32];
#pragma unroll
        for (int i = 0; i < 32; ++i) hr[i] = h0s[dd * 32 + i];
        float arr[32];
#pragma unroll
        for (int f = 0; f < 26; ++f) {
            float s = bias;
#pragma unroll
            for (int j = 0; j < 7; ++j) s += w1r[j] * hr[f + j];
            arr[f] = fast_tanh(s);
        }
#pragma unroll
        for (int f = 26; f < 32; ++f) arr[f] = -2.0f;
        bitonic_asc<32>(arr);
        unsigned short* row = &t1s[dd * 1800 + c];
#pragma unroll
        for (int r = 0; r < 23; ++r) row[(2 + r) * 64] = f2bf(arr[31 - r]);
    }
    __syncthreads();

    // ---- phase B: conv2 MFMA ----
    {
        const int lane = tid & 63;
        const int w = tid >> 6;
        const int quad = lane >> 4;
        const int m = lane & 15;
        const int e = m >> 3, dd = m & 7;
        const int n = lane & 15;

        short8 Bf0[10], Bf1[10];
#pragma unroll
        for (int ks = 0; ks < 10; ++ks) {
            Bf0[ks] = *reinterpret_cast<const short8*>(w2b + (n * 320 + ks * 32 + quad * 8));
            Bf1[ks] = *reinterpret_cast<const short8*>(w2b + ((16 + n) * 320 + ks * 32 + quad * 8));
        }
        float bias0 = cb2[n], bias1 = cb2[16 + n];

#pragma unroll
        for (int pi = 0; pi < 3; ++pi) {
            int p = w + pi * 4;            // fpair 0..11
            int f0 = 2 * p;
            f32x4 acc0 = {bias0, bias0, bias0, bias0};
            f32x4 acc1 = {bias1, bias1, bias1, bias1};
            const unsigned short* abase = &t1s[dd * 1800 + (f0 + e) * 64 + quad * 8];
#pragma unroll
            for (int ks = 0; ks < 10; ++ks) {
                short8 af = *reinterpret_cast<const short8*>(abase + ks * 32);
                acc0 = __builtin_amdgcn_mfma_f32_16x16x32_bf16(af, Bf0[ks], acc0, 0, 0, 0);
                acc1 = __builtin_amdgcn_mfma_f32_16x16x32_bf16(af, Bf1[ks], acc1, 0, 0, 0);
            }
#pragma unroll
            for (int r = 0; r < 4; ++r) {
                int mm = quad * 4 + r;
                int ee = mm >> 3, dw = mm & 7;
                int f = f0 + ee;
                if (f < 23) {
                    y2s[(dw * 32 + n) * 25 + f]      = f2bf(fast_tanh(acc0[r]));
                    y2s[(dw * 32 + 16 + n) * 25 + f] = f2bf(fast_tanh(acc1[r]));
                }
            }
        }
    }
    __syncthreads();

    // ---- phase C: top-8 of 23 per (dd, c2) ----
    {
        int dd = tid >> 5, c2 = tid & 31;
        float a[32];
        const unsigned short* src = &y2s[(dd * 32 + c2) * 25];
#pragma unroll
        for (int f = 0; f < 23; ++f) a[f] = bf2f(src[f]);
#pragma unroll
        for (int f = 23; f < 32; ++f) a[f] = -2.0f;
        bitonic_asc<32>(a);
        unsigned short* row = &t2bf[dd * 328 + c2];
#pragma unroll
        for (int r = 0; r < 8; ++r) row[(1 + r) * 32] = f2bf(a[31 - r]);
    }
    __syncthreads();

    // ---- phase D: conv3 MFMA (wave w -> fpair w, f = 2w+e) ----
    {
        const int lane = tid & 63;
        const int w = tid >> 6;
        const int quad = lane >> 4;
        const int m = lane & 15;
        const int e = m >> 3, dd = m & 7;
        const int n = lane & 15;
        int f0 = 2 * w;

        f32x4 acc;
        float bias = cb3[n];
        acc[0] = bias; acc[1] = bias; acc[2] = bias; acc[3] = bias;
        const unsigned short* abase = &t2bf[dd * 328 + (f0 + e) * 32 + quad * 8];
#pragma unroll
        for (int ks = 0; ks < 3; ++ks) {
            short8 af = *reinterpret_cast<const short8*>(abase + ks * 32);
            short8 bf = *reinterpret_cast<const short8*>(w3b + (n * 96 + ks * 32 + quad * 8));
            acc = __builtin_amdgcn_mfma_f32_16x16x32_bf16(af, bf, acc, 0, 0, 0);
        }
#pragma unroll
        for (int r = 0; r < 4; ++r) {
            int mm = quad * 4 + r;
            int ee = mm >> 3, dw = mm & 7;
            int f = f0 + ee;
            y3s[dw * 128 + n * 8 + f] = fast_tanh(acc[r]);
        }
    }
    __syncthreads();

    // ---- phase E: top-3 of 8 per (dd, c3) -> hmat ----
    if (tid < 128) {
        int dd = tid >> 4, c3 = tid & 15;
        float a[8];
#pragma unroll
        for (int f = 0; f < 8; ++f) a[f] = y3s[dd * 128 + c3 * 8 + f];
        bitonic_asc<8>(a);
        float* orow = &hmat[(size_t)b * LDH + c3 * 192 + d0 + dd];
        orow[0]   = a[7];
        orow[64]  = a[6];
        orow[128] = a[5];
    }
}

// ---------------------------------------------------------------------------
// fp32 tiled GEMM (unchanged from R1)
// ---------------------------------------------------------------------------
template<bool APPLY>
__global__ __launch_bounds__(256) void gemm_kernel(
    const float* __restrict__ A, int lda, int K,
    const float* __restrict__ Bm, int ldb,
    const float* __restrict__ scl, const float* __restrict__ sft,
    float* __restrict__ C, int N)
{
    __shared__ __align__(16) float As[16 * 68];
    __shared__ __align__(16) float Bs[16 * 68];
    const int tid = threadIdx.x;
    const int row0 = blockIdx.y * 64;
    const int n0 = blockIdx.x * 64;
    const int ty = tid >> 4, tx = tid & 15;

    float acc[4][4];
#pragma unroll
    for (int i = 0; i < 4; ++i)
#pragma unroll
        for (int j = 0; j < 4; ++j) acc[i][j] = 0.f;

    const int kk_a = tid & 15, rb_a = tid >> 4;
    const int kr_b = tid >> 4, nb_b = (tid & 15) * 4;

    for (int k0 = 0; k0 < K; k0 += 16) {
        __syncthreads();
        {
            int k = k0 + kk_a;
            bool ok = (k < K);
            float sc = 0.f, sh = 0.f;
            if (APPLY && ok) { sc = scl[k]; sh = sft[k]; }
#pragma unroll
            for (int p = 0; p < 4; ++p) {
                int r = rb_a + p * 16;
                float v = 0.f;
                if (ok) {
                    v = A[(size_t)(row0 + r) * lda + k];
                    if (APPLY) v = fast_tanh(v * sc + sh);
                }
                As[kk_a * 68 + r] = v;
            }
        }
        {
            int k = k0 + kr_b;
            float4 bv = make_float4(0.f, 0.f, 0.f, 0.f);
            if (k < K) bv = *reinterpret_cast<const float4*>(&Bm[(size_t)k * ldb + n0 + nb_b]);
            *reinterpret_cast<float4*>(&Bs[kr_b * 68 + nb_b]) = bv;
        }
        __syncthreads();
#pragma unroll
        for (int kk = 0; kk < 16; ++kk) {
            float4 av = *reinterpret_cast<const float4*>(&As[kk * 68 + ty * 4]);
            float4 bv = *reinterpret_cast<const float4*>(&Bs[kk * 68 + tx * 4]);
            float aa[4] = {av.x, av.y, av.z, av.w};
            float bb[4] = {bv.x, bv.y, bv.z, bv.w};
#pragma unroll
            for (int i = 0; i < 4; ++i)
#pragma unroll
                for (int j = 0; j < 4; ++j) acc[i][j] += aa[i] * bb[j];
        }
    }

#pragma unroll
    for (int i = 0; i < 4; ++i) {
        float4 ov = make_float4(acc[i][0], acc[i][1], acc[i][2], acc[i][3]);
        *reinterpret_cast<float4*>(&C[(size_t)(row0 + ty * 4 + i) * N + n0 + tx * 4]) = ov;
    }
}

__global__ void bnstats_kernel(const float* __restrict__ z, int ncols,
                               float* __restrict__ sums, float* __restrict__ sumsq)
{
    int col = threadIdx.x;
    int r0 = blockIdx.x * 256;
    float s = 0.f, q = 0.f;
    for (int i = 0; i < 256; ++i) {
        float v = z[(size_t)(r0 + i) * ncols + col];
        s += v; q += v * v;
    }
    atomicAdd(&sums[col], s);
    atomicAdd(&sumsq[col], q);
}

__global__ void bnfin_kernel(const float* __restrict__ sums, const float* __restrict__ sumsq,
                             const float* __restrict__ g, const float* __restrict__ be,
                             int ncols, float* __restrict__ scl, float* __restrict__ sft)
{
    int i = threadIdx.x + blockIdx.x * blockDim.x;
    if (i < ncols) {
        float mu = sums[i] * (1.0f / 4096.0f);
        float var = sumsq[i] * (1.0f / 4096.0f) - mu * mu;
        float s = g[i] * rsqrtf(var + 1e-5f);
        scl[i] = s;
        sft[i] = be[i] - mu * s;
    }
}

__global__ __launch_bounds__(256) void final_kernel(
    const float* __restrict__ z2, const float* __restrict__ scl, const float* __restrict__ sft,
    const float* __restrict__ W3, const float* __restrict__ b3, float* __restrict__ out)
{
    int lane = threadIdx.x & 63;
    int wv = threadIdx.x >> 6;
    int r = blockIdx.x * 4 + wv;
    float p = 0.f;
#pragma unroll
    for (int t = 0; t < 2; ++t) {
        int n = lane + t * 64;
        p += fast_tanh(z2[(size_t)r * 128 + n] * scl[n] + sft[n]) * W3[n];
    }
#pragma unroll
    for (int off = 32; off > 0; off >>= 1) p += __shfl_down(p, off);
    if (lane == 0) out[r] = p + b3[0];
}

extern "C" void kernel_launch(void* const* d_in, const int* in_sizes, int n_in,
                              void* d_out, int out_size, void* d_ws, size_t ws_size,
                              hipStream_t stream) {
    const int*   sparse = (const int*)  d_in[0];
    const float* dense  = (const float*)d_in[1];
    const float* tables = (const float*)d_in[2];
    const float* cw1    = (const float*)d_in[3];
    const float* cb1    = (const float*)d_in[4];
    const float* cw2    = (const float*)d_in[5];
    const float* cb2    = (const float*)d_in[6];
    const float* cw3    = (const float*)d_in[7];
    const float* cb3    = (const float*)d_in[8];
    const float* W1     = (const float*)d_in[9];
    const float* g1     = (const float*)d_in[11];
    const float* be1    = (const float*)d_in[12];
    const float* W2     = (const float*)d_in[13];
    const float* g2     = (const float*)d_in[15];
    const float* be2    = (const float*)d_in[16];
    const float* W3     = (const float*)d_in[17];
    const float* b3     = (const float*)d_in[18];
    float* out = (float*)d_out;

    float* ws   = (float*)d_ws;
    float* hmat = ws;                                  // 4096*3088
    float* z1   = hmat + (size_t)B_SZ * LDH;           // 4096*256
    float* z2   = z1 + (size_t)B_SZ * 256;             // 4096*128
    float* w1t  = z2 + (size_t)B_SZ * 128;             // 448 fp32
    unsigned short* w2b = (unsigned short*)(w1t + 448);    // 10240 bf16 (5120 f)
    unsigned short* w3b = (unsigned short*)(w1t + 448 + 5120); // 1536 bf16 (768 f)
    float* sums = w1t + 448 + 5120 + 768;              // 768
    float* a1   = sums + 768;                          // 256
    float* c1   = a1 + 256;                            // 256
    float* a2   = c1 + 256;                            // 128
    float* c2v  = a2 + 128;                            // 128

    prep_kernel<<<259, 256, 0, stream>>>(cw1, cw2, cw3, dense, w1t, w2b, w3b, sums, hmat);

    cnn_kernel<<<dim3(8, B_SZ), 256, 0, stream>>>(sparse, tables, w1t, cb1,
                                                  w2b, cb2, w3b, cb3, hmat);

    gemm_kernel<false><<<dim3(4, 64), 256, 0, stream>>>(hmat, LDH, DIN, W1, 256,
                                                        nullptr, nullptr, z1, 256);
    bnstats_kernel<<<16, 256, 0, stream>>>(z1, 256, sums, sums + 256);
    bnfin_kernel<<<1, 256, 0, stream>>>(sums, sums + 256, g1, be1, 256, a1, c1);

    gemm_kernel<true><<<dim3(2, 64), 256, 0, stream>>>(z1, 256, 256, W2, 128,
                                                       a1, c1, z2, 128);
    bnstats_kernel<<<16, 128, 0, stream>>>(z2, 128, sums + 512, sums + 640);
    bnfin_kernel<<<1, 128, 0, stream>>>(sums + 512, sums + 640, g2, be2, 128, a2, c2v);

    final_kernel<<<1024, 256, 0, stream>>>(z2, a2, c2v, W3, b3, out);
}